// Round 12
// baseline (326.864 us; speedup 1.0000x reference)
//
#include <hip/hip_runtime.h>
#include <math.h>

typedef unsigned short u16;
typedef __attribute__((ext_vector_type(8))) __bf16 bf16x8v;
typedef __attribute__((ext_vector_type(8))) unsigned short ushort8v;
typedef __attribute__((ext_vector_type(4))) unsigned short ushort4v;
typedef __attribute__((ext_vector_type(4))) float f32x4v;

#define D_EMBD 1024
#define NHEADS 16
#define DHEAD  64
#define DFF    4096
#define BATCHN 2
#define SEQL   2048
#define TOK    (BATCHN*SEQL)

#define EPI_BF16_GELU    2
#define EPI_BF16_QKV     3   // bf16 out; Q columns (gc<1024) scaled by 0.125*log2e
#define EPI_BF16_PART    5   // split-K: bf16 partial at Cb + z*M*N

__device__ __forceinline__ float bf2f(u16 s) {
  return __builtin_bit_cast(float, (unsigned)s << 16);
}
__device__ __forceinline__ u16 f2bf(float f) {
  unsigned u = __builtin_bit_cast(unsigned, f);
  unsigned r = u + 0x7fffu + ((u >> 16) & 1u);
  return (u16)(r >> 16);
}
__device__ __forceinline__ u16 f2bf_trunc(float f) {
  return (u16)(__builtin_bit_cast(unsigned, f) >> 16);
}

// async global->LDS, 16B per lane; LDS dest = wave-uniform base + lane*16
#define GLOAD16(gp, lp)                                                        \
  __builtin_amdgcn_global_load_lds(                                            \
      (__attribute__((address_space(1))) void*)(void*)(gp),                    \
      (__attribute__((address_space(3))) void*)(void*)(lp), 16, 0, 0)

// ---------------------------------------------------------------------------
// prep: ONE launch does all weight f32->bf16 conversions AND LayerNorm1.
// ---------------------------------------------------------------------------
__global__ __launch_bounds__(256) void prep_kernel(const float* __restrict__ wq,
                                                   const float* __restrict__ wk,
                                                   const float* __restrict__ wv,
                                                   const float* __restrict__ wo,
                                                   const float* __restrict__ w1,
                                                   const float* __restrict__ w2,
                                                   u16* __restrict__ wcat,
                                                   u16* __restrict__ wob,
                                                   u16* __restrict__ w1b,
                                                   u16* __restrict__ w2b,
                                                   const float* __restrict__ x,
                                                   const float* __restrict__ sc,
                                                   const float* __restrict__ sh,
                                                   u16* __restrict__ xn) {
  int bid = blockIdx.x, tid = threadIdx.x;
  if (bid < 12288) {
    const float* src;
    u16* dst;
    int loc;
    if (bid < 4096) {
      int seg = bid >> 10;
      loc = (bid & 1023) * 256 + tid;
      src = (seg == 0) ? wq : (seg == 1) ? wk : (seg == 2) ? wv : wo;
      dst = (seg == 0) ? wcat : (seg == 1) ? wcat + 1048576
                              : (seg == 2) ? wcat + 2097152 : wob;
    } else if (bid < 8192) {
      loc = (bid - 4096) * 256 + tid;
      src = w1; dst = w1b;
    } else {
      loc = (bid - 8192) * 256 + tid;
      src = w2; dst = w2b;
    }
    float4 v = ((const float4*)src)[loc];
    ushort4 o;
    o.x = f2bf(v.x); o.y = f2bf(v.y); o.z = f2bf(v.z); o.w = f2bf(v.w);
    ((ushort4*)dst)[loc] = o;
    return;
  }
  // ---- LayerNorm over D=1024, one block per row ----
  int row = bid - 12288;
  const float4* xr = (const float4*)(x + (size_t)row * D_EMBD);
  float4 v = xr[tid];
  float s  = (v.x + v.y) + (v.z + v.w);
  float s2 = (v.x * v.x + v.y * v.y) + (v.z * v.z + v.w * v.w);
#pragma unroll
  for (int off = 32; off; off >>= 1) {
    s  += __shfl_xor(s, off, 64);
    s2 += __shfl_xor(s2, off, 64);
  }
  __shared__ float rs[4], rs2[4];
  int wave = tid >> 6, lane = tid & 63;
  if (lane == 0) { rs[wave] = s; rs2[wave] = s2; }
  __syncthreads();
  s  = (rs[0] + rs[1]) + (rs[2] + rs[3]);
  s2 = (rs2[0] + rs2[1]) + (rs2[2] + rs2[3]);
  float mean = s * (1.f / 1024.f);
  float var  = s2 * (1.f / 1024.f) - mean * mean;
  float rstd = rsqrtf(var + 1e-6f);
  float4 scv = ((const float4*)sc)[tid];
  float4 shv = ((const float4*)sh)[tid];
  ushort4 o;
  o.x = f2bf((v.x - mean) * rstd * scv.x + shv.x);
  o.y = f2bf((v.y - mean) * rstd * scv.y + shv.y);
  o.z = f2bf((v.z - mean) * rstd * scv.z + shv.z);
  o.w = f2bf((v.w - mean) * rstd * scv.w + shv.w);
  ((ushort4*)(xn + (size_t)row * D_EMBD))[tid] = o;
}

// Fused: h = x + (sum of 4 bf16 wo partials) + bo; write hbuf(f32);
// then LayerNorm(h) -> ybuf(bf16). One block per row.
__global__ __launch_bounds__(256) void ln2f_kernel(const u16* __restrict__ parts,
                                                   const float* __restrict__ x,
                                                   const float* __restrict__ bo,
                                                   const float* __restrict__ sc,
                                                   const float* __restrict__ sh,
                                                   float* __restrict__ hbuf,
                                                   u16* __restrict__ ybuf) {
  int row = blockIdx.x, tid = threadIdx.x;
  size_t base4 = (size_t)row * 256 + tid;   // float4 / ushort4 index
  float4 v = ((const float4*)x)[base4];
  float4 bv = ((const float4*)bo)[tid];
  v.x += bv.x; v.y += bv.y; v.z += bv.z; v.w += bv.w;
#pragma unroll
  for (int p = 0; p < 4; ++p) {
    ushort4 u = ((const ushort4*)parts)[(size_t)p * 1048576 + base4];
    v.x += bf2f(u.x); v.y += bf2f(u.y); v.z += bf2f(u.z); v.w += bf2f(u.w);
  }
  ((float4*)hbuf)[base4] = v;
  float s  = (v.x + v.y) + (v.z + v.w);
  float s2 = (v.x * v.x + v.y * v.y) + (v.z * v.z + v.w * v.w);
#pragma unroll
  for (int off = 32; off; off >>= 1) {
    s  += __shfl_xor(s, off, 64);
    s2 += __shfl_xor(s2, off, 64);
  }
  __shared__ float rs[4], rs2[4];
  int wave = tid >> 6, lane = tid & 63;
  if (lane == 0) { rs[wave] = s; rs2[wave] = s2; }
  __syncthreads();
  s  = (rs[0] + rs[1]) + (rs[2] + rs[3]);
  s2 = (rs2[0] + rs2[1]) + (rs2[2] + rs2[3]);
  float mean = s * (1.f / 1024.f);
  float var  = s2 * (1.f / 1024.f) - mean * mean;
  float rstd = rsqrtf(var + 1e-6f);
  float4 scv = ((const float4*)sc)[tid];
  float4 shv = ((const float4*)sh)[tid];
  ushort4 o;
  o.x = f2bf((v.x - mean) * rstd * scv.x + shv.x);
  o.y = f2bf((v.y - mean) * rstd * scv.y + shv.y);
  o.z = f2bf((v.z - mean) * rstd * scv.z + shv.z);
  o.w = f2bf((v.w - mean) * rstd * scv.w + shv.w);
  ((ushort4*)ybuf)[base4] = o;
}

// split-K reduce for w2: out = sum_{4} bf16 partials + bias + resid
__global__ __launch_bounds__(256) void reduce_w2_kernel(const u16* __restrict__ parts,
                                                        const float* __restrict__ resid,
                                                        const float* __restrict__ bias,
                                                        float* __restrict__ out) {
  int i = blockIdx.x * 256 + threadIdx.x;
  float4 r = ((const float4*)resid)[i];
  float4 bi = ((const float4*)bias)[i & 255];
  float s0 = 0, s1 = 0, s2 = 0, s3 = 0;
#pragma unroll
  for (int p = 0; p < 4; ++p) {
    ushort4 u = ((const ushort4*)parts)[(size_t)p * 1048576 + i];
    s0 += bf2f(u.x); s1 += bf2f(u.y); s2 += bf2f(u.z); s3 += bf2f(u.w);
  }
  float4 o = {s0 + r.x + bi.x, s1 + r.y + bi.y, s2 + r.z + bi.z, s3 + r.w + bi.w};
  ((float4*)out)[i] = o;
}

// ============================================================================
// 256x256-tile GEMM — ROUND-7/10 PROVEN SCHEDULE, byte-identical restore
// (decoupled from the qkv kernel to avoid template codegen perturbation).
// 2 phases/tile, 32-MFMA clusters; vmcnt(4) gate at P2; T1 XCD swizzle;
// st-swizzled LDS via pre-swizzled global source.
// ============================================================================
#define GBAR  __builtin_amdgcn_s_barrier()
#define LGKM0 do { asm volatile("s_waitcnt lgkmcnt(0)" ::: "memory"); \
                   __builtin_amdgcn_sched_barrier(0); } while (0)

template <int EPI>
__global__ __launch_bounds__(512, 2) void gemm256(const u16* __restrict__ A,
                                                  const u16* __restrict__ W,
                                                  u16* __restrict__ Cb,
                                                  const float* __restrict__ bias,
                                                  int M, int N, int K) {
  __shared__ __align__(16) u16 sm[65536];  // 128 KiB
  const int tid = threadIdx.x;
  const int wave = tid >> 6, lane = tid & 63;
  const int lr = lane & 15, quad = lane >> 4;
  const int wm = wave >> 2, wn = wave & 3;
  // T1: XCD-chunked swizzle (all launch grids have nwg % 8 == 0)
  const int gx = gridDim.x, gy = gridDim.y;
  const int nwg = gx * gy * gridDim.z;
  const int bid = blockIdx.x + gx * (blockIdx.y + gy * blockIdx.z);
  const int swz = (bid & 7) * (nwg >> 3) + (bid >> 3);
  const int bx = swz % gx;
  const int r1 = swz / gx;
  const int by = r1 % gy, bz = r1 / gy;
  const int m0 = by * 256, n0 = bx * 256;
  const int KC = K / gridDim.z;
  const int kbeg = bz * KC;
  const int NT = KC >> 6;
  const size_t poff = (size_t)bz * ((size_t)M * N);

  const int r8 = lane >> 3;                 // row within 8-row group
  const int sslot = (lane & 7) ^ r8;        // pre-swizzled source 16B slot
  const int rb0 = wave * 2;
  const int sx = lr & 7;

  auto stA = [&](int bb, int h, int tk) {
#pragma unroll
    for (int s = 0; s < 2; ++s) {
      const u16* gp = A + (size_t)(m0 + h * 128 + (rb0 + s) * 8 + r8) * K +
                      (kbeg + tk * 64 + sslot * 8);
      GLOAD16(gp, (char*)sm + bb * 65536 + h * 16384 + (rb0 + s) * 1024);
    }
  };
  auto stB = [&](int bb, int h, int tk) {
#pragma unroll
    for (int s = 0; s < 2; ++s) {
      const u16* gp = W + (size_t)(n0 + h * 128 + (rb0 + s) * 8 + r8) * K +
                      (kbeg + tk * 64 + sslot * 8);
      GLOAD16(gp, (char*)sm + bb * 65536 + 32768 + h * 16384 + (rb0 + s) * 1024);
    }
  };
  auto ldA = [&](bf16x8v (&av)[4][2], int mh, int cur) {
#pragma unroll
    for (int j2 = 0; j2 < 4; ++j2) {
      int row = (2 * (mh * 4 + j2) + wm) * 16 + lr;
#pragma unroll
      for (int kk = 0; kk < 2; ++kk) {
        int slot = (kk * 4 + quad) ^ sx;
        av[j2][kk] = *(const bf16x8v*)(sm + cur * 32768 + row * 64 + slot * 8);
      }
    }
  };
  auto ldB = [&](bf16x8v (&bv)[2][2], int nh, int cur) {
#pragma unroll
    for (int i2 = 0; i2 < 2; ++i2) {
      int row = (wn + 4 * (nh * 2 + i2)) * 16 + lr;
#pragma unroll
      for (int kk = 0; kk < 2; ++kk) {
        int slot = (kk * 4 + quad) ^ sx;
        bv[i2][kk] = *(const bf16x8v*)(sm + cur * 32768 + 16384 + row * 64 + slot * 8);
      }
    }
  };

  f32x4v acc[8][4];
#pragma unroll
  for (int j = 0; j < 8; ++j)
#pragma unroll
    for (int i = 0; i < 4; ++i) {
      f32x4v z = {0.f, 0.f, 0.f, 0.f};
      acc[j][i] = z;
    }
  bf16x8v av[4][2], bv0[2][2], bv1[2][2];

  // 32-MFMA cluster for row-half mh against both column halves
  auto MMA32 = [&](int mh) {
    GBAR;
    LGKM0;
    __builtin_amdgcn_s_setprio(1);
#pragma unroll
    for (int j2 = 0; j2 < 4; ++j2)
#pragma unroll
      for (int i2 = 0; i2 < 2; ++i2)
#pragma unroll
        for (int kk = 0; kk < 2; ++kk) {
          acc[mh * 4 + j2][i2] = __builtin_amdgcn_mfma_f32_16x16x32_bf16(
              av[j2][kk], bv0[i2][kk], acc[mh * 4 + j2][i2], 0, 0, 0);
          acc[mh * 4 + j2][2 + i2] = __builtin_amdgcn_mfma_f32_16x16x32_bf16(
              av[j2][kk], bv1[i2][kk], acc[mh * 4 + j2][2 + i2], 0, 0, 0);
        }
    __builtin_amdgcn_s_setprio(0);
    __builtin_amdgcn_sched_barrier(0);
    GBAR;
  };

  // prologue: tile0 fully (oldest 8 loads), then t1.A0, t1.B1
  stA(0, 0, 0); stB(0, 0, 0); stA(0, 1, 0); stB(0, 1, 0);
  stA(1, 0, 1); stB(1, 1, 1);
  asm volatile("s_waitcnt vmcnt(4)" ::: "memory");  // tile0 landed
  GBAR;

  for (int t = 0; t < NT; ++t) {
    const int cur = t & 1, nb = cur ^ 1;
    const bool p1 = (t + 1 < NT), p2 = (t + 2 < NT);
    // ---- P1: (A0 x B0) + (A0 x B1) ----
    ldA(av, 0, cur); ldB(bv0, 0, cur); ldB(bv1, 1, cur);
    if (p1) { stB(nb, 0, t + 1); stA(nb, 1, t + 1); }
    MMA32(0);
    // ---- P2: (A1 x B0) + (A1 x B1) ----
    ldA(av, 1, cur);
    if (p2) { stA(cur, 0, t + 2); stB(cur, 1, t + 2); }
    if (p2) { asm volatile("s_waitcnt vmcnt(4)" ::: "memory"); }
    else    { asm volatile("s_waitcnt vmcnt(0)" ::: "memory"); }
    MMA32(1);
  }

  const bool qsc = (EPI == EPI_BF16_QKV) && (n0 < 1024);  // block-uniform
#pragma unroll
  for (int j = 0; j < 8; ++j) {
    int gr = m0 + (2 * j + wm) * 16 + quad * 4;
#pragma unroll
    for (int i = 0; i < 4; ++i) {
      int gc = n0 + (wn + 4 * i) * 16 + lr;
      float bi = 0.f;
      if constexpr (EPI == EPI_BF16_GELU) bi = bias[gc];
#pragma unroll
      for (int r = 0; r < 4; ++r) {
        size_t idx = (size_t)(gr + r) * N + gc;
        float v = acc[j][i][r];
        if constexpr (EPI == EPI_BF16_PART) {
          Cb[poff + idx] = f2bf(v);
        } else if constexpr (EPI == EPI_BF16_QKV) {
          Cb[idx] = f2bf(qsc ? v * 0.18033688011112042f : v);
        } else {  // EPI_BF16_GELU
          v += bi;
          float z = 0.7978845608028654f * (v + 0.044715f * v * v * v);
          float tt = 2.f / (1.f + __expf(-2.f * z)) - 1.f;
          Cb[idx] = f2bf(0.5f * v * (1.f + tt));
        }
      }
    }
  }
}

// ============================================================================
// gemm192 — dedicated QKV kernel: 256x192 tiles, grid (16,16)=256 blocks =
// exactly 1/CU (the old (12,16) grid left 64 CUs idle). Same frozen 2-phase
// schedule shape; B staged as 3x64-row chunks; MFMA cluster ordered
// j2->kk->ii so consecutive MFMAs hit different accumulators (distance 3).
// Ledger: P1 stages t+1.{B0,B1,B2,A1}(5); P2 stages t+2.A0(2), gate vmcnt(2)
// drains all of t+1, leaves t+2.A0 in flight. Q-scale 0.125*log2e on gc<1024.
// ============================================================================
__global__ __launch_bounds__(512, 2) void gemm192(const u16* __restrict__ A,
                                                  const u16* __restrict__ W,
                                                  u16* __restrict__ Cb,
                                                  int M, int N, int K) {
  __shared__ __align__(16) u16 sm[65536];  // 128 KiB
  const int tid = threadIdx.x;
  const int wave = tid >> 6, lane = tid & 63;
  const int lr = lane & 15, quad = lane >> 4;
  const int wm = wave >> 2, wn = wave & 3;
  const int gx = gridDim.x, gy = gridDim.y;
  const int nwg = gx * gy;
  const int bid = blockIdx.x + gx * blockIdx.y;
  const int swz = (bid & 7) * (nwg >> 3) + (bid >> 3);
  const int bx = swz % gx;
  const int by = swz / gx;
  const int m0 = by * 256, n0 = bx * 192;
  const int NT = K >> 6;

  const int r8 = lane >> 3;
  const int sslot = (lane & 7) ^ r8;
  const int rb0 = wave * 2;
  const int sx = lr & 7;

  auto stA = [&](int bb, int h, int tk) {
#pragma unroll
    for (int s = 0; s < 2; ++s) {
      const u16* gp = A + (size_t)(m0 + h * 128 + (rb0 + s) * 8 + r8) * K +
                      (tk * 64 + sslot * 8);
      GLOAD16(gp, (char*)sm + bb * 65536 + h * 16384 + (rb0 + s) * 1024);
    }
  };
  auto stBch = [&](int bb, int ch, int tk) {
    const u16* gp = W + (size_t)(n0 + ch * 64 + wave * 8 + r8) * K +
                    (tk * 64 + sslot * 8);
    GLOAD16(gp, (char*)sm + bb * 65536 + 32768 + ch * 8192 + wave * 1024);
  };
  auto ldA = [&](bf16x8v (&av)[4][2], int mh, int cur) {
#pragma unroll
    for (int j2 = 0; j2 < 4; ++j2) {
      int row = (2 * (mh * 4 + j2) + wm) * 16 + lr;
#pragma unroll
      for (int kk = 0; kk < 2; ++kk) {
        int slot = (kk * 4 + quad) ^ sx;
        av[j2][kk] = *(const bf16x8v*)(sm + cur * 32768 + row * 64 + slot * 8);
      }
    }
  };
  auto ldB3 = [&](bf16x8v (&bv)[3][2], int cur) {
#pragma unroll
    for (int ii = 0; ii < 3; ++ii) {
      int row = (wn + 4 * ii) * 16 + lr;
#pragma unroll
      for (int kk = 0; kk < 2; ++kk) {
        int slot = (kk * 4 + quad) ^ sx;
        bv[ii][kk] = *(const bf16x8v*)(sm + cur * 32768 + 16384 + row * 64 + slot * 8);
      }
    }
  };

  f32x4v acc[8][3];
#pragma unroll
  for (int j = 0; j < 8; ++j)
#pragma unroll
    for (int i = 0; i < 3; ++i) {
      f32x4v z = {0.f, 0.f, 0.f, 0.f};
      acc[j][i] = z;
    }
  bf16x8v av[4][2], bv[3][2];

  // 24-MFMA cluster: j2 -> kk -> ii (same-acc dependency distance 3)
  auto MMA24 = [&](int mh) {
    GBAR;
    LGKM0;
    __builtin_amdgcn_s_setprio(1);
#pragma unroll
    for (int j2 = 0; j2 < 4; ++j2)
#pragma unroll
      for (int kk = 0; kk < 2; ++kk)
#pragma unroll
        for (int ii = 0; ii < 3; ++ii)
          acc[mh * 4 + j2][ii] = __builtin_amdgcn_mfma_f32_16x16x32_bf16(
              av[j2][kk], bv[ii][kk], acc[mh * 4 + j2][ii], 0, 0, 0);
    __builtin_amdgcn_s_setprio(0);
    __builtin_amdgcn_sched_barrier(0);
    GBAR;
  };

  // prologue: tile0 fully (7 loads), then t1.A0; vmcnt(2)
  stA(0, 0, 0); stBch(0, 0, 0); stBch(0, 1, 0); stBch(0, 2, 0); stA(0, 1, 0);
  stA(1, 0, 1);
  asm volatile("s_waitcnt vmcnt(2)" ::: "memory");
  GBAR;

  for (int t = 0; t < NT; ++t) {
    const int cur = t & 1, nb = cur ^ 1;
    const bool p1 = (t + 1 < NT), p2 = (t + 2 < NT);
    // ---- P1: A0 x all B; stage t+1.{B0,B1,B2,A1} ----
    ldA(av, 0, cur); ldB3(bv, cur);
    if (p1) { stBch(nb, 0, t + 1); stBch(nb, 1, t + 1); stBch(nb, 2, t + 1);
              stA(nb, 1, t + 1); }
    MMA24(0);
    // ---- P2: A1 x all B; stage t+2.A0; gate vmcnt(2) ----
    ldA(av, 1, cur);
    if (p2) { stA(cur, 0, t + 2); }
    if (p2) { asm volatile("s_waitcnt vmcnt(2)" ::: "memory"); }
    else    { asm volatile("s_waitcnt vmcnt(0)" ::: "memory"); }
    MMA24(1);
  }

#pragma unroll
  for (int j = 0; j < 8; ++j) {
    int gr = m0 + (2 * j + wm) * 16 + quad * 4;
#pragma unroll
    for (int i = 0; i < 3; ++i) {
      int gc = n0 + (wn + 4 * i) * 16 + lr;
      // fragment-uniform Q-scale test (1024 boundary is 16-aligned)
      const bool qsc = (n0 + (wn + 4 * i) * 16) < 1024;
#pragma unroll
      for (int r = 0; r < 4; ++r) {
        size_t idx = (size_t)(gr + r) * N + gc;
        float v = acc[j][i][r];
        // folds 1/sqrt(dhead)=0.125 AND log2(e): softmax runs in exp2 domain
        Cb[idx] = f2bf(qsc ? v * 0.18033688011112042f : v);
      }
    }
  }
}

// ---------------- MFMA flash attention (causal), S^T formulation ----------
// ROUND-1 PROVEN STRUCTURE + log2 softmax (r9) + defer-max (r10), verified.
#define VTS 72
__device__ __forceinline__ void stage_k(const u16* Kbase, int ks, u16* kfbuf,
                                        int wave, int lr, int quad) {
#pragma unroll
  for (int p = 0; p < 2; ++p) {
    int q = wave * 2 + p;
    int key = ((q >> 1) << 4) + lr;
    int c8 = ((q & 1) << 2) + quad;
    GLOAD16(Kbase + (size_t)(ks + key) * 3072 + c8 * 8, (char*)kfbuf + q * 1024);
  }
}
__device__ __forceinline__ void load_v(const u16* Vbase, int ks, int vkey0, int vc8,
                                       ushort8v& va, ushort8v& vb) {
  va = *(const ushort8v*)(Vbase + (size_t)(ks + vkey0) * 3072 + vc8 * 8);
  vb = *(const ushort8v*)(Vbase + (size_t)(ks + vkey0 + 1) * 3072 + vc8 * 8);
}
__device__ __forceinline__ void write_vt(u16* vt, int vc8, int vcol,
                                         ushort8v va, ushort8v vb) {
#pragma unroll
  for (int j = 0; j < 8; ++j) {
    unsigned pk = (unsigned)va[j] | ((unsigned)vb[j] << 16);
    *(unsigned*)(vt + (size_t)(vc8 * 8 + j) * VTS + vcol) = pk;
  }
}

__global__ __launch_bounds__(256) void attn_kernel(const u16* __restrict__ qkv,
                                                   u16* __restrict__ ctx) {
  __shared__ u16 Kf[2][4096];        // 16 KB, fragment order
  __shared__ u16 Vt[2][64 * VTS];    // 18 KB, V^T swizzled
  int tid = threadIdx.x;
  int wave = tid >> 6, lane = tid & 63;
  int lr = lane & 15, quad = lane >> 4;
  int id = blockIdx.x;
  int bh = id & 31;
  int t = 31 - (id >> 5);            // LPT: longest q-tiles dispatch first
  int b = bh >> 4, h = bh & 15;
  int q0 = t * 64;
  const u16* qkvb = qkv + (size_t)(b * SEQL) * 3072;
  int qrow = q0 + wave * 16 + lr;
  const u16* Qp = qkvb + (size_t)qrow * 3072 + h * 64 + quad * 8;
  bf16x8v qf0 = *(const bf16x8v*)(Qp);        // Q pre-scaled by 0.125*log2e
  bf16x8v qf1 = *(const bf16x8v*)(Qp + 32);
  const u16* Kbase = qkvb + 1024 + h * 64;
  const u16* Vbase = qkvb + 2048 + h * 64;
  int vkey0 = (tid >> 3) * 2, vc8 = tid & 7;
  int vcol = vkey0 ^ (vc8 << 2);

  float m = -INFINITY, l = 0.f;
  f32x4v accO[4];
#pragma unroll
  for (int r = 0; r < 4; r++) {
    f32x4v z = {0.f, 0.f, 0.f, 0.f};
    accO[r] = z;
  }

  int nkt = t + 1;
  {
    stage_k(Kbase, 0, Kf[0], wave, lr, quad);
    ushort8v va, vb;
    load_v(Vbase, 0, vkey0, vc8, va, vb);
    write_vt(Vt[0], vc8, vcol, va, vb);
  }
  __syncthreads();

  for (int kt = 0; kt < nkt; ++kt) {
    int cur = kt & 1, nxt = cur ^ 1;
    ushort8v va, vb;
    bool pre = (kt + 1 < nkt);
    if (pre) {
      stage_k(Kbase, (kt + 1) * 64, Kf[nxt], wave, lr, quad);
      load_v(Vbase, (kt + 1) * 64, vkey0, vc8, va, vb);
    }
    const bf16x8v* Kc = (const bf16x8v*)Kf[cur];
    const u16* Vc = Vt[cur];
    // ---- S^T = K Q^T (log2 domain) ----
    f32x4v accS[4];
#pragma unroll
    for (int jb = 0; jb < 4; jb++) {
      f32x4v z = {0.f, 0.f, 0.f, 0.f};
      accS[jb] = z;
    }
#pragma unroll
    for (int jb = 0; jb < 4; jb++) {
      accS[jb] = __builtin_amdgcn_mfma_f32_16x16x32_bf16(Kc[((jb * 2 + 0) << 6) + lane], qf0, accS[jb], 0, 0, 0);
      accS[jb] = __builtin_amdgcn_mfma_f32_16x16x32_bf16(Kc[((jb * 2 + 1) << 6) + lane], qf1, accS[jb], 0, 0, 0);
    }
    if (kt == t) {  // diagonal tile: mask key > q
#pragma unroll
      for (int jb = 0; jb < 4; jb++)
#pragma unroll
        for (int r = 0; r < 4; r++)
          if (jb * 16 + quad * 4 + r > wave * 16 + lr) accS[jb][r] = -INFINITY;
    }
    // ---- per-lane online softmax (q = lane&15), exp2 domain ----
    float smax = accS[0][0];
#pragma unroll
    for (int jb = 0; jb < 4; jb++)
#pragma unroll
      for (int r = 0; r < 4; r++) smax = fmaxf(smax, accS[jb][r]);
    smax = fmaxf(smax, __shfl_xor(smax, 16, 64));
    smax = fmaxf(smax, __shfl_xor(smax, 32, 64));
    // defer-max: only rescale when some row's max grew past m+8
    if (!__all(smax <= m + 8.f)) {
      float mn = fmaxf(m, smax);
      float alpha = __builtin_amdgcn_exp2f(m - mn);
      m = mn;
      l *= alpha;
      float ar[4];
#pragma unroll
      for (int r = 0; r < 4; r++) ar[r] = __shfl(alpha, quad * 4 + r, 16);
#pragma unroll
      for (int nb = 0; nb < 4; nb++)
#pragma unroll
        for (int r = 0; r < 4; r++) accO[nb][r] *= ar[r];
    }
    float ps = 0.f;
#pragma unroll
    for (int jb = 0; jb < 4; jb++)
#pragma unroll
      for (int r = 0; r < 4; r++) {
        accS[jb][r] = __builtin_amdgcn_exp2f(accS[jb][r] - m);
        ps += accS[jb][r];
      }
    ps += __shfl_xor(ps, 16, 64);
    ps += __shfl_xor(ps, 32, 64);
    l += ps;
    // ---- O += P V ----
#pragma unroll
    for (int kk = 0; kk < 2; ++kk) {
      ushort8v pp;
#pragma unroll
      for (int j = 0; j < 4; ++j) {
        pp[j]     = f2bf_trunc(accS[2 * kk][j]);
        pp[j + 4] = f2bf_trunc(accS[2 * kk + 1][j]);
      }
      bf16x8v pav = __builtin_bit_cast(bf16x8v, pp);
#pragma unroll
      for (int nb = 0; nb < 4; nb++) {
        int dim = nb * 16 + lr;
        int f = (nb * 2 + (lr >> 3)) & 7;
        int col1 = (kk * 32 + quad * 4) ^ (f << 2);
        ushort4v v0 = *(const ushort4v*)(Vc + dim * VTS + col1);
        ushort4v v1 = *(const ushort4v*)(Vc + dim * VTS + (col1 ^ 16));
        ushort8v vv;
#pragma unroll
        for (int j = 0; j < 4; ++j) { vv[j] = v0[j]; vv[j + 4] = v1[j]; }
        accO[nb] = __builtin_amdgcn_mfma_f32_16x16x32_bf16(pav, __builtin_bit_cast(bf16x8v, vv), accO[nb], 0, 0, 0);
      }
    }
    if (pre) write_vt(Vt[nxt], vc8, vcol, va, vb);
    __syncthreads();  // single barrier per tile
  }
  float linv = 1.f / l;
  float rr[4];
#pragma unroll
  for (int r = 0; r < 4; r++) rr[r] = __shfl(linv, quad * 4 + r, 16);
#pragma unroll
  for (int nb = 0; nb < 4; nb++)
#pragma unroll
    for (int r = 0; r < 4; r++) {
      int rowg = q0 + wave * 16 + quad * 4 + r;
      ctx[(size_t)(b * SEQL + rowg) * D_EMBD + h * 64 + nb * 16 + lr] =
          f2bf(accO[nb][r] * rr[r]);
    }
}

extern "C" void kernel_launch(void* const* d_in, const int* in_sizes, int n_in,
                              void* d_out, int out_size, void* d_ws, size_t ws_size,
                              hipStream_t stream) {
  const float* x    = (const float*)d_in[0];
  const float* wq   = (const float*)d_in[1];
  const float* wk   = (const float*)d_in[2];
  const float* wv   = (const float*)d_in[3];
  const float* wo   = (const float*)d_in[4];
  const float* bo   = (const float*)d_in[5];
  const float* w1   = (const float*)d_in[6];
  const float* b1   = (const float*)d_in[7];
  const float* w2   = (const float*)d_in[8];
  const float* b2   = (const float*)d_in[9];
  const float* ln1s = (const float*)d_in[10];
  const float* ln1b = (const float*)d_in[11];
  const float* ln2s = (const float*)d_in[12];
  const float* ln2b = (const float*)d_in[13];
  float* out = (float*)d_out;

  char* base = (char*)d_ws;
  size_t off = 0;
  auto alloc = [&](size_t bytes) {
    char* r = base + off;
    off += (bytes + 255) & ~(size_t)255;
    return r;
  };
  u16*   wcat = (u16*)alloc((size_t)3072 * 1024 * 2);
  u16*   wob  = (u16*)alloc((size_t)1024 * 1024 * 2);
  u16*   w1b  = (u16*)alloc((size_t)4096 * 1024 * 2);
  u16*   w2b  = (u16*)alloc((size_t)1024 * 4096 * 2);
  u16*   xn   = (u16*)alloc((size_t)TOK * 1024 * 2);   // 8 MB
  u16*   qkv  = (u16*)alloc((size_t)TOK * 3072 * 2);   // 24 MB
  u16*   ctx  = (u16*)alloc((size_t)TOK * 1024 * 2);
  float* hbuf = (float*)alloc((size_t)TOK * 1024 * 4);
  u16*   ybuf = (u16*)alloc((size_t)TOK * 1024 * 2);
  u16*   gbuf = (u16*)alloc((size_t)TOK * 4096 * 2);
  // split-K bf16 partials (4 x 8 MB) overlay the dead xn+qkv region (32 MB):
  //   wo partials live attn->ln2f; w2 partials live w2gemm->reduce_w2.
  u16* woP = (u16*)xn;
  u16* w2P = (u16*)xn;

  // ONE prep launch: all weight conversions + LayerNorm1
  prep_kernel<<<16384, 256, 0, stream>>>(wq, wk, wv, wo, w1, w2,
                                         wcat, wob, w1b, w2b,
                                         x, ln1s, ln1b, xn);
  // qkv: dedicated 256x192-tile kernel -> (16,16) = 256 blocks = 1/CU exact
  gemm192<<<dim3(16, 16), 512, 0, stream>>>(xn, wcat, qkv, TOK, 3072, 1024);
  attn_kernel<<<1024, 256, 0, stream>>>(qkv, ctx);
  // wo: split-K=4 bf16 partials (qkv region now dead), KC=256 -> NT=4
  gemm256<EPI_BF16_PART><<<dim3(4, 16, 4), 512, 0, stream>>>(
      ctx, wob, woP, nullptr, TOK, 1024, 1024);
  // fused: h = x + sum(partials) + bo -> hbuf; ln2(h) -> ybuf
  ln2f_kernel<<<TOK, 256, 0, stream>>>(woP, x, bo, ln2s, ln2b, hbuf, ybuf);
  gemm256<EPI_BF16_GELU><<<dim3(16, 16), 512, 0, stream>>>(
      ybuf, w1b, gbuf, b1, TOK, 4096, 1024);
  gemm256<EPI_BF16_PART><<<dim3(4, 16, 4), 512, 0, stream>>>(
      gbuf, w2b, w2P, nullptr, TOK, 1024, 4096);
  reduce_w2_kernel<<<4096, 256, 0, stream>>>(w2P, hbuf, b2, out);
}

// Round 13
// 319.968 us; speedup vs baseline: 1.0216x; 1.0216x over previous
//
#include <hip/hip_runtime.h>
#include <math.h>

typedef unsigned short u16;
typedef __attribute__((ext_vector_type(8))) __bf16 bf16x8v;
typedef __attribute__((ext_vector_type(8))) unsigned short ushort8v;
typedef __attribute__((ext_vector_type(4))) unsigned short ushort4v;
typedef __attribute__((ext_vector_type(4))) float f32x4v;

#define D_EMBD 1024
#define NHEADS 16
#define DHEAD  64
#define DFF    4096
#define BATCHN 2
#define SEQL   2048
#define TOK    (BATCHN*SEQL)

#define EPI_BF16_GELU    2
#define EPI_BF16_QKV     3   // bf16 out; Q columns (gc<1024) scaled by 0.125*log2e
#define EPI_BF16_PART    5   // split-K: bf16 partial at Cb + z*M*N

__device__ __forceinline__ float bf2f(u16 s) {
  return __builtin_bit_cast(float, (unsigned)s << 16);
}
__device__ __forceinline__ u16 f2bf(float f) {
  unsigned u = __builtin_bit_cast(unsigned, f);
  unsigned r = u + 0x7fffu + ((u >> 16) & 1u);
  return (u16)(r >> 16);
}
__device__ __forceinline__ u16 f2bf_trunc(float f) {
  return (u16)(__builtin_bit_cast(unsigned, f) >> 16);
}

// async global->LDS, 16B per lane; LDS dest = wave-uniform base + lane*16
#define GLOAD16(gp, lp)                                                        \
  __builtin_amdgcn_global_load_lds(                                            \
      (__attribute__((address_space(1))) void*)(void*)(gp),                    \
      (__attribute__((address_space(3))) void*)(void*)(lp), 16, 0, 0)

// ---------------------------------------------------------------------------
// prep: ONE launch does all weight f32->bf16 conversions AND LayerNorm1.
// ---------------------------------------------------------------------------
__global__ __launch_bounds__(256) void prep_kernel(const float* __restrict__ wq,
                                                   const float* __restrict__ wk,
                                                   const float* __restrict__ wv,
                                                   const float* __restrict__ wo,
                                                   const float* __restrict__ w1,
                                                   const float* __restrict__ w2,
                                                   u16* __restrict__ wcat,
                                                   u16* __restrict__ wob,
                                                   u16* __restrict__ w1b,
                                                   u16* __restrict__ w2b,
                                                   const float* __restrict__ x,
                                                   const float* __restrict__ sc,
                                                   const float* __restrict__ sh,
                                                   u16* __restrict__ xn) {
  int bid = blockIdx.x, tid = threadIdx.x;
  if (bid < 12288) {
    const float* src;
    u16* dst;
    int loc;
    if (bid < 4096) {
      int seg = bid >> 10;
      loc = (bid & 1023) * 256 + tid;
      src = (seg == 0) ? wq : (seg == 1) ? wk : (seg == 2) ? wv : wo;
      dst = (seg == 0) ? wcat : (seg == 1) ? wcat + 1048576
                              : (seg == 2) ? wcat + 2097152 : wob;
    } else if (bid < 8192) {
      loc = (bid - 4096) * 256 + tid;
      src = w1; dst = w1b;
    } else {
      loc = (bid - 8192) * 256 + tid;
      src = w2; dst = w2b;
    }
    float4 v = ((const float4*)src)[loc];
    ushort4 o;
    o.x = f2bf(v.x); o.y = f2bf(v.y); o.z = f2bf(v.z); o.w = f2bf(v.w);
    ((ushort4*)dst)[loc] = o;
    return;
  }
  // ---- LayerNorm over D=1024, one block per row ----
  int row = bid - 12288;
  const float4* xr = (const float4*)(x + (size_t)row * D_EMBD);
  float4 v = xr[tid];
  float s  = (v.x + v.y) + (v.z + v.w);
  float s2 = (v.x * v.x + v.y * v.y) + (v.z * v.z + v.w * v.w);
#pragma unroll
  for (int off = 32; off; off >>= 1) {
    s  += __shfl_xor(s, off, 64);
    s2 += __shfl_xor(s2, off, 64);
  }
  __shared__ float rs[4], rs2[4];
  int wave = tid >> 6, lane = tid & 63;
  if (lane == 0) { rs[wave] = s; rs2[wave] = s2; }
  __syncthreads();
  s  = (rs[0] + rs[1]) + (rs[2] + rs[3]);
  s2 = (rs2[0] + rs2[1]) + (rs2[2] + rs2[3]);
  float mean = s * (1.f / 1024.f);
  float var  = s2 * (1.f / 1024.f) - mean * mean;
  float rstd = rsqrtf(var + 1e-6f);
  float4 scv = ((const float4*)sc)[tid];
  float4 shv = ((const float4*)sh)[tid];
  ushort4 o;
  o.x = f2bf((v.x - mean) * rstd * scv.x + shv.x);
  o.y = f2bf((v.y - mean) * rstd * scv.y + shv.y);
  o.z = f2bf((v.z - mean) * rstd * scv.z + shv.z);
  o.w = f2bf((v.w - mean) * rstd * scv.w + shv.w);
  ((ushort4*)(xn + (size_t)row * D_EMBD))[tid] = o;
}

// Fused: h = x + (sum of 4 bf16 wo partials) + bo; write hbuf(f32);
// then LayerNorm(h) -> ybuf(bf16). One block per row.
__global__ __launch_bounds__(256) void ln2f_kernel(const u16* __restrict__ parts,
                                                   const float* __restrict__ x,
                                                   const float* __restrict__ bo,
                                                   const float* __restrict__ sc,
                                                   const float* __restrict__ sh,
                                                   float* __restrict__ hbuf,
                                                   u16* __restrict__ ybuf) {
  int row = blockIdx.x, tid = threadIdx.x;
  size_t base4 = (size_t)row * 256 + tid;   // float4 / ushort4 index
  float4 v = ((const float4*)x)[base4];
  float4 bv = ((const float4*)bo)[tid];
  v.x += bv.x; v.y += bv.y; v.z += bv.z; v.w += bv.w;
#pragma unroll
  for (int p = 0; p < 4; ++p) {
    ushort4 u = ((const ushort4*)parts)[(size_t)p * 1048576 + base4];
    v.x += bf2f(u.x); v.y += bf2f(u.y); v.z += bf2f(u.z); v.w += bf2f(u.w);
  }
  ((float4*)hbuf)[base4] = v;
  float s  = (v.x + v.y) + (v.z + v.w);
  float s2 = (v.x * v.x + v.y * v.y) + (v.z * v.z + v.w * v.w);
#pragma unroll
  for (int off = 32; off; off >>= 1) {
    s  += __shfl_xor(s, off, 64);
    s2 += __shfl_xor(s2, off, 64);
  }
  __shared__ float rs[4], rs2[4];
  int wave = tid >> 6, lane = tid & 63;
  if (lane == 0) { rs[wave] = s; rs2[wave] = s2; }
  __syncthreads();
  s  = (rs[0] + rs[1]) + (rs[2] + rs[3]);
  s2 = (rs2[0] + rs2[1]) + (rs2[2] + rs2[3]);
  float mean = s * (1.f / 1024.f);
  float var  = s2 * (1.f / 1024.f) - mean * mean;
  float rstd = rsqrtf(var + 1e-6f);
  float4 scv = ((const float4*)sc)[tid];
  float4 shv = ((const float4*)sh)[tid];
  ushort4 o;
  o.x = f2bf((v.x - mean) * rstd * scv.x + shv.x);
  o.y = f2bf((v.y - mean) * rstd * scv.y + shv.y);
  o.z = f2bf((v.z - mean) * rstd * scv.z + shv.z);
  o.w = f2bf((v.w - mean) * rstd * scv.w + shv.w);
  ((ushort4*)ybuf)[base4] = o;
}

// split-K reduce for w2: out = sum_{4} bf16 partials + bias + resid
__global__ __launch_bounds__(256) void reduce_w2_kernel(const u16* __restrict__ parts,
                                                        const float* __restrict__ resid,
                                                        const float* __restrict__ bias,
                                                        float* __restrict__ out) {
  int i = blockIdx.x * 256 + threadIdx.x;
  float4 r = ((const float4*)resid)[i];
  float4 bi = ((const float4*)bias)[i & 255];
  float s0 = 0, s1 = 0, s2 = 0, s3 = 0;
#pragma unroll
  for (int p = 0; p < 4; ++p) {
    ushort4 u = ((const ushort4*)parts)[(size_t)p * 1048576 + i];
    s0 += bf2f(u.x); s1 += bf2f(u.y); s2 += bf2f(u.z); s3 += bf2f(u.w);
  }
  float4 o = {s0 + r.x + bi.x, s1 + r.y + bi.y, s2 + r.z + bi.z, s3 + r.w + bi.w};
  ((float4*)out)[i] = o;
}

// ============================================================================
// 256x256-tile GEMM — ROUND-7/10 PROVEN SCHEDULE, frozen.
// ============================================================================
#define GBAR  __builtin_amdgcn_s_barrier()
#define LGKM0 do { asm volatile("s_waitcnt lgkmcnt(0)" ::: "memory"); \
                   __builtin_amdgcn_sched_barrier(0); } while (0)

template <int EPI>
__global__ __launch_bounds__(512, 2) void gemm256(const u16* __restrict__ A,
                                                  const u16* __restrict__ W,
                                                  u16* __restrict__ Cb,
                                                  const float* __restrict__ bias,
                                                  int M, int N, int K) {
  __shared__ __align__(16) u16 sm[65536];  // 128 KiB
  const int tid = threadIdx.x;
  const int wave = tid >> 6, lane = tid & 63;
  const int lr = lane & 15, quad = lane >> 4;
  const int wm = wave >> 2, wn = wave & 3;
  // T1: XCD-chunked swizzle (all launch grids have nwg % 8 == 0)
  const int gx = gridDim.x, gy = gridDim.y;
  const int nwg = gx * gy * gridDim.z;
  const int bid = blockIdx.x + gx * (blockIdx.y + gy * blockIdx.z);
  const int swz = (bid & 7) * (nwg >> 3) + (bid >> 3);
  const int bx = swz % gx;
  const int r1 = swz / gx;
  const int by = r1 % gy, bz = r1 / gy;
  const int m0 = by * 256, n0 = bx * 256;
  const int KC = K / gridDim.z;
  const int kbeg = bz * KC;
  const int NT = KC >> 6;
  const size_t poff = (size_t)bz * ((size_t)M * N);

  const int r8 = lane >> 3;                 // row within 8-row group
  const int sslot = (lane & 7) ^ r8;        // pre-swizzled source 16B slot
  const int rb0 = wave * 2;
  const int sx = lr & 7;

  auto stA = [&](int bb, int h, int tk) {
#pragma unroll
    for (int s = 0; s < 2; ++s) {
      const u16* gp = A + (size_t)(m0 + h * 128 + (rb0 + s) * 8 + r8) * K +
                      (kbeg + tk * 64 + sslot * 8);
      GLOAD16(gp, (char*)sm + bb * 65536 + h * 16384 + (rb0 + s) * 1024);
    }
  };
  auto stB = [&](int bb, int h, int tk) {
#pragma unroll
    for (int s = 0; s < 2; ++s) {
      const u16* gp = W + (size_t)(n0 + h * 128 + (rb0 + s) * 8 + r8) * K +
                      (kbeg + tk * 64 + sslot * 8);
      GLOAD16(gp, (char*)sm + bb * 65536 + 32768 + h * 16384 + (rb0 + s) * 1024);
    }
  };
  auto ldA = [&](bf16x8v (&av)[4][2], int mh, int cur) {
#pragma unroll
    for (int j2 = 0; j2 < 4; ++j2) {
      int row = (2 * (mh * 4 + j2) + wm) * 16 + lr;
#pragma unroll
      for (int kk = 0; kk < 2; ++kk) {
        int slot = (kk * 4 + quad) ^ sx;
        av[j2][kk] = *(const bf16x8v*)(sm + cur * 32768 + row * 64 + slot * 8);
      }
    }
  };
  auto ldB = [&](bf16x8v (&bv)[2][2], int nh, int cur) {
#pragma unroll
    for (int i2 = 0; i2 < 2; ++i2) {
      int row = (wn + 4 * (nh * 2 + i2)) * 16 + lr;
#pragma unroll
      for (int kk = 0; kk < 2; ++kk) {
        int slot = (kk * 4 + quad) ^ sx;
        bv[i2][kk] = *(const bf16x8v*)(sm + cur * 32768 + 16384 + row * 64 + slot * 8);
      }
    }
  };

  f32x4v acc[8][4];
#pragma unroll
  for (int j = 0; j < 8; ++j)
#pragma unroll
    for (int i = 0; i < 4; ++i) {
      f32x4v z = {0.f, 0.f, 0.f, 0.f};
      acc[j][i] = z;
    }
  bf16x8v av[4][2], bv0[2][2], bv1[2][2];

  // 32-MFMA cluster for row-half mh against both column halves
  auto MMA32 = [&](int mh) {
    GBAR;
    LGKM0;
    __builtin_amdgcn_s_setprio(1);
#pragma unroll
    for (int j2 = 0; j2 < 4; ++j2)
#pragma unroll
      for (int i2 = 0; i2 < 2; ++i2)
#pragma unroll
        for (int kk = 0; kk < 2; ++kk) {
          acc[mh * 4 + j2][i2] = __builtin_amdgcn_mfma_f32_16x16x32_bf16(
              av[j2][kk], bv0[i2][kk], acc[mh * 4 + j2][i2], 0, 0, 0);
          acc[mh * 4 + j2][2 + i2] = __builtin_amdgcn_mfma_f32_16x16x32_bf16(
              av[j2][kk], bv1[i2][kk], acc[mh * 4 + j2][2 + i2], 0, 0, 0);
        }
    __builtin_amdgcn_s_setprio(0);
    __builtin_amdgcn_sched_barrier(0);
    GBAR;
  };

  // prologue: tile0 fully (oldest 8 loads), then t1.A0, t1.B1
  stA(0, 0, 0); stB(0, 0, 0); stA(0, 1, 0); stB(0, 1, 0);
  stA(1, 0, 1); stB(1, 1, 1);
  asm volatile("s_waitcnt vmcnt(4)" ::: "memory");  // tile0 landed
  GBAR;

  for (int t = 0; t < NT; ++t) {
    const int cur = t & 1, nb = cur ^ 1;
    const bool p1 = (t + 1 < NT), p2 = (t + 2 < NT);
    // ---- P1: (A0 x B0) + (A0 x B1) ----
    ldA(av, 0, cur); ldB(bv0, 0, cur); ldB(bv1, 1, cur);
    if (p1) { stB(nb, 0, t + 1); stA(nb, 1, t + 1); }
    MMA32(0);
    // ---- P2: (A1 x B0) + (A1 x B1) ----
    ldA(av, 1, cur);
    if (p2) { stA(cur, 0, t + 2); stB(cur, 1, t + 2); }
    if (p2) { asm volatile("s_waitcnt vmcnt(4)" ::: "memory"); }
    else    { asm volatile("s_waitcnt vmcnt(0)" ::: "memory"); }
    MMA32(1);
  }

  const bool qsc = (EPI == EPI_BF16_QKV) && (n0 < 1024);  // block-uniform
#pragma unroll
  for (int j = 0; j < 8; ++j) {
    int gr = m0 + (2 * j + wm) * 16 + quad * 4;
#pragma unroll
    for (int i = 0; i < 4; ++i) {
      int gc = n0 + (wn + 4 * i) * 16 + lr;
      float bi = 0.f;
      if constexpr (EPI == EPI_BF16_GELU) bi = bias[gc];
#pragma unroll
      for (int r = 0; r < 4; ++r) {
        size_t idx = (size_t)(gr + r) * N + gc;
        float v = acc[j][i][r];
        if constexpr (EPI == EPI_BF16_PART) {
          Cb[poff + idx] = f2bf(v);
        } else if constexpr (EPI == EPI_BF16_QKV) {
          Cb[idx] = f2bf(qsc ? v * 0.18033688011112042f : v);
        } else {  // EPI_BF16_GELU
          v += bi;
          float z = 0.7978845608028654f * (v + 0.044715f * v * v * v);
          float tt = 2.f / (1.f + __expf(-2.f * z)) - 1.f;
          Cb[idx] = f2bf(0.5f * v * (1.f + tt));
        }
      }
    }
  }
}

// ============================================================================
// gemm192 — dedicated QKV kernel: 256x192 tiles, grid (16,16)=256 blocks =
// exactly 1/CU. Frozen 2-phase schedule shape; B staged as 3x64-row chunks;
// MFMA cluster j2->kk->ii (same-acc dependency distance 3).
// ============================================================================
__global__ __launch_bounds__(512, 2) void gemm192(const u16* __restrict__ A,
                                                  const u16* __restrict__ W,
                                                  u16* __restrict__ Cb,
                                                  int M, int N, int K) {
  __shared__ __align__(16) u16 sm[65536];  // 128 KiB
  const int tid = threadIdx.x;
  const int wave = tid >> 6, lane = tid & 63;
  const int lr = lane & 15, quad = lane >> 4;
  const int wm = wave >> 2, wn = wave & 3;
  const int gx = gridDim.x, gy = gridDim.y;
  const int nwg = gx * gy;
  const int bid = blockIdx.x + gx * blockIdx.y;
  const int swz = (bid & 7) * (nwg >> 3) + (bid >> 3);
  const int bx = swz % gx;
  const int by = swz / gx;
  const int m0 = by * 256, n0 = bx * 192;
  const int NT = K >> 6;

  const int r8 = lane >> 3;
  const int sslot = (lane & 7) ^ r8;
  const int rb0 = wave * 2;
  const int sx = lr & 7;

  auto stA = [&](int bb, int h, int tk) {
#pragma unroll
    for (int s = 0; s < 2; ++s) {
      const u16* gp = A + (size_t)(m0 + h * 128 + (rb0 + s) * 8 + r8) * K +
                      (tk * 64 + sslot * 8);
      GLOAD16(gp, (char*)sm + bb * 65536 + h * 16384 + (rb0 + s) * 1024);
    }
  };
  auto stBch = [&](int bb, int ch, int tk) {
    const u16* gp = W + (size_t)(n0 + ch * 64 + wave * 8 + r8) * K +
                    (tk * 64 + sslot * 8);
    GLOAD16(gp, (char*)sm + bb * 65536 + 32768 + ch * 8192 + wave * 1024);
  };
  auto ldA = [&](bf16x8v (&av)[4][2], int mh, int cur) {
#pragma unroll
    for (int j2 = 0; j2 < 4; ++j2) {
      int row = (2 * (mh * 4 + j2) + wm) * 16 + lr;
#pragma unroll
      for (int kk = 0; kk < 2; ++kk) {
        int slot = (kk * 4 + quad) ^ sx;
        av[j2][kk] = *(const bf16x8v*)(sm + cur * 32768 + row * 64 + slot * 8);
      }
    }
  };
  auto ldB3 = [&](bf16x8v (&bv)[3][2], int cur) {
#pragma unroll
    for (int ii = 0; ii < 3; ++ii) {
      int row = (wn + 4 * ii) * 16 + lr;
#pragma unroll
      for (int kk = 0; kk < 2; ++kk) {
        int slot = (kk * 4 + quad) ^ sx;
        bv[ii][kk] = *(const bf16x8v*)(sm + cur * 32768 + 16384 + row * 64 + slot * 8);
      }
    }
  };

  f32x4v acc[8][3];
#pragma unroll
  for (int j = 0; j < 8; ++j)
#pragma unroll
    for (int i = 0; i < 3; ++i) {
      f32x4v z = {0.f, 0.f, 0.f, 0.f};
      acc[j][i] = z;
    }
  bf16x8v av[4][2], bv[3][2];

  // 24-MFMA cluster: j2 -> kk -> ii (same-acc dependency distance 3)
  auto MMA24 = [&](int mh) {
    GBAR;
    LGKM0;
    __builtin_amdgcn_s_setprio(1);
#pragma unroll
    for (int j2 = 0; j2 < 4; ++j2)
#pragma unroll
      for (int kk = 0; kk < 2; ++kk)
#pragma unroll
        for (int ii = 0; ii < 3; ++ii)
          acc[mh * 4 + j2][ii] = __builtin_amdgcn_mfma_f32_16x16x32_bf16(
              av[j2][kk], bv[ii][kk], acc[mh * 4 + j2][ii], 0, 0, 0);
    __builtin_amdgcn_s_setprio(0);
    __builtin_amdgcn_sched_barrier(0);
    GBAR;
  };

  // prologue: tile0 fully (7 loads), then t1.A0; vmcnt(2)
  stA(0, 0, 0); stBch(0, 0, 0); stBch(0, 1, 0); stBch(0, 2, 0); stA(0, 1, 0);
  stA(1, 0, 1);
  asm volatile("s_waitcnt vmcnt(2)" ::: "memory");
  GBAR;

  for (int t = 0; t < NT; ++t) {
    const int cur = t & 1, nb = cur ^ 1;
    const bool p1 = (t + 1 < NT), p2 = (t + 2 < NT);
    // ---- P1: A0 x all B; stage t+1.{B0,B1,B2,A1} ----
    ldA(av, 0, cur); ldB3(bv, cur);
    if (p1) { stBch(nb, 0, t + 1); stBch(nb, 1, t + 1); stBch(nb, 2, t + 1);
              stA(nb, 1, t + 1); }
    MMA24(0);
    // ---- P2: A1 x all B; stage t+2.A0; gate vmcnt(2) ----
    ldA(av, 1, cur);
    if (p2) { stA(cur, 0, t + 2); }
    if (p2) { asm volatile("s_waitcnt vmcnt(2)" ::: "memory"); }
    else    { asm volatile("s_waitcnt vmcnt(0)" ::: "memory"); }
    MMA24(1);
  }

#pragma unroll
  for (int j = 0; j < 8; ++j) {
    int gr = m0 + (2 * j + wm) * 16 + quad * 4;
#pragma unroll
    for (int i = 0; i < 3; ++i) {
      int gc = n0 + (wn + 4 * i) * 16 + lr;
      // fragment-uniform Q-scale test (1024 boundary is 16-aligned)
      const bool qsc = (n0 + (wn + 4 * i) * 16) < 1024;
#pragma unroll
      for (int r = 0; r < 4; ++r) {
        size_t idx = (size_t)(gr + r) * N + gc;
        float v = acc[j][i][r];
        // folds 1/sqrt(dhead)=0.125 AND log2(e): softmax runs in exp2 domain
        Cb[idx] = f2bf(qsc ? v * 0.18033688011112042f : v);
      }
    }
  }
}

// ---------------- MFMA flash attention (causal), S^T formulation ----------
// ROUND-1 PROVEN STRUCTURE + log2 softmax (r9) + defer-max (r10).
// ROUND-13 single change: T5 s_setprio(1)/(0) around the QK^T and PV MFMA
// clusters. attn's regime matches m191's proven +4-7%: 4 independent
// blocks/CU at different pipeline phases give the CU scheduler real
// arbitration between MFMA-entering and staging/softmax waves.
#define VTS 72
__device__ __forceinline__ void stage_k(const u16* Kbase, int ks, u16* kfbuf,
                                        int wave, int lr, int quad) {
#pragma unroll
  for (int p = 0; p < 2; ++p) {
    int q = wave * 2 + p;
    int key = ((q >> 1) << 4) + lr;
    int c8 = ((q & 1) << 2) + quad;
    GLOAD16(Kbase + (size_t)(ks + key) * 3072 + c8 * 8, (char*)kfbuf + q * 1024);
  }
}
__device__ __forceinline__ void load_v(const u16* Vbase, int ks, int vkey0, int vc8,
                                       ushort8v& va, ushort8v& vb) {
  va = *(const ushort8v*)(Vbase + (size_t)(ks + vkey0) * 3072 + vc8 * 8);
  vb = *(const ushort8v*)(Vbase + (size_t)(ks + vkey0 + 1) * 3072 + vc8 * 8);
}
__device__ __forceinline__ void write_vt(u16* vt, int vc8, int vcol,
                                         ushort8v va, ushort8v vb) {
#pragma unroll
  for (int j = 0; j < 8; ++j) {
    unsigned pk = (unsigned)va[j] | ((unsigned)vb[j] << 16);
    *(unsigned*)(vt + (size_t)(vc8 * 8 + j) * VTS + vcol) = pk;
  }
}

__global__ __launch_bounds__(256) void attn_kernel(const u16* __restrict__ qkv,
                                                   u16* __restrict__ ctx) {
  __shared__ u16 Kf[2][4096];        // 16 KB, fragment order
  __shared__ u16 Vt[2][64 * VTS];    // 18 KB, V^T swizzled
  int tid = threadIdx.x;
  int wave = tid >> 6, lane = tid & 63;
  int lr = lane & 15, quad = lane >> 4;
  int id = blockIdx.x;
  int bh = id & 31;
  int t = 31 - (id >> 5);            // LPT: longest q-tiles dispatch first
  int b = bh >> 4, h = bh & 15;
  int q0 = t * 64;
  const u16* qkvb = qkv + (size_t)(b * SEQL) * 3072;
  int qrow = q0 + wave * 16 + lr;
  const u16* Qp = qkvb + (size_t)qrow * 3072 + h * 64 + quad * 8;
  bf16x8v qf0 = *(const bf16x8v*)(Qp);        // Q pre-scaled by 0.125*log2e
  bf16x8v qf1 = *(const bf16x8v*)(Qp + 32);
  const u16* Kbase = qkvb + 1024 + h * 64;
  const u16* Vbase = qkvb + 2048 + h * 64;
  int vkey0 = (tid >> 3) * 2, vc8 = tid & 7;
  int vcol = vkey0 ^ (vc8 << 2);

  float m = -INFINITY, l = 0.f;
  f32x4v accO[4];
#pragma unroll
  for (int r = 0; r < 4; r++) {
    f32x4v z = {0.f, 0.f, 0.f, 0.f};
    accO[r] = z;
  }

  int nkt = t + 1;
  {
    stage_k(Kbase, 0, Kf[0], wave, lr, quad);
    ushort8v va, vb;
    load_v(Vbase, 0, vkey0, vc8, va, vb);
    write_vt(Vt[0], vc8, vcol, va, vb);
  }
  __syncthreads();

  for (int kt = 0; kt < nkt; ++kt) {
    int cur = kt & 1, nxt = cur ^ 1;
    ushort8v va, vb;
    bool pre = (kt + 1 < nkt);
    if (pre) {
      stage_k(Kbase, (kt + 1) * 64, Kf[nxt], wave, lr, quad);
      load_v(Vbase, (kt + 1) * 64, vkey0, vc8, va, vb);
    }
    const bf16x8v* Kc = (const bf16x8v*)Kf[cur];
    const u16* Vc = Vt[cur];
    // ---- S^T = K Q^T (log2 domain) ----
    f32x4v accS[4];
#pragma unroll
    for (int jb = 0; jb < 4; jb++) {
      f32x4v z = {0.f, 0.f, 0.f, 0.f};
      accS[jb] = z;
    }
    __builtin_amdgcn_s_setprio(1);
#pragma unroll
    for (int jb = 0; jb < 4; jb++) {
      accS[jb] = __builtin_amdgcn_mfma_f32_16x16x32_bf16(Kc[((jb * 2 + 0) << 6) + lane], qf0, accS[jb], 0, 0, 0);
      accS[jb] = __builtin_amdgcn_mfma_f32_16x16x32_bf16(Kc[((jb * 2 + 1) << 6) + lane], qf1, accS[jb], 0, 0, 0);
    }
    __builtin_amdgcn_s_setprio(0);
    if (kt == t) {  // diagonal tile: mask key > q
#pragma unroll
      for (int jb = 0; jb < 4; jb++)
#pragma unroll
        for (int r = 0; r < 4; r++)
          if (jb * 16 + quad * 4 + r > wave * 16 + lr) accS[jb][r] = -INFINITY;
    }
    // ---- per-lane online softmax (q = lane&15), exp2 domain ----
    float smax = accS[0][0];
#pragma unroll
    for (int jb = 0; jb < 4; jb++)
#pragma unroll
      for (int r = 0; r < 4; r++) smax = fmaxf(smax, accS[jb][r]);
    smax = fmaxf(smax, __shfl_xor(smax, 16, 64));
    smax = fmaxf(smax, __shfl_xor(smax, 32, 64));
    // defer-max: only rescale when some row's max grew past m+8
    if (!__all(smax <= m + 8.f)) {
      float mn = fmaxf(m, smax);
      float alpha = __builtin_amdgcn_exp2f(m - mn);
      m = mn;
      l *= alpha;
      float ar[4];
#pragma unroll
      for (int r = 0; r < 4; r++) ar[r] = __shfl(alpha, quad * 4 + r, 16);
#pragma unroll
      for (int nb = 0; nb < 4; nb++)
#pragma unroll
        for (int r = 0; r < 4; r++) accO[nb][r] *= ar[r];
    }
    float ps = 0.f;
#pragma unroll
    for (int jb = 0; jb < 4; jb++)
#pragma unroll
      for (int r = 0; r < 4; r++) {
        accS[jb][r] = __builtin_amdgcn_exp2f(accS[jb][r] - m);
        ps += accS[jb][r];
      }
    ps += __shfl_xor(ps, 16, 64);
    ps += __shfl_xor(ps, 32, 64);
    l += ps;
    // ---- O += P V ----
    __builtin_amdgcn_s_setprio(1);
#pragma unroll
    for (int kk = 0; kk < 2; ++kk) {
      ushort8v pp;
#pragma unroll
      for (int j = 0; j < 4; ++j) {
        pp[j]     = f2bf_trunc(accS[2 * kk][j]);
        pp[j + 4] = f2bf_trunc(accS[2 * kk + 1][j]);
      }
      bf16x8v pav = __builtin_bit_cast(bf16x8v, pp);
#pragma unroll
      for (int nb = 0; nb < 4; nb++) {
        int dim = nb * 16 + lr;
        int f = (nb * 2 + (lr >> 3)) & 7;
        int col1 = (kk * 32 + quad * 4) ^ (f << 2);
        ushort4v v0 = *(const ushort4v*)(Vc + dim * VTS + col1);
        ushort4v v1 = *(const ushort4v*)(Vc + dim * VTS + (col1 ^ 16));
        ushort8v vv;
#pragma unroll
        for (int j = 0; j < 4; ++j) { vv[j] = v0[j]; vv[j + 4] = v1[j]; }
        accO[nb] = __builtin_amdgcn_mfma_f32_16x16x32_bf16(pav, __builtin_bit_cast(bf16x8v, vv), accO[nb], 0, 0, 0);
      }
    }
    __builtin_amdgcn_s_setprio(0);
    if (pre) write_vt(Vt[nxt], vc8, vcol, va, vb);
    __syncthreads();  // single barrier per tile
  }
  float linv = 1.f / l;
  float rr[4];
#pragma unroll
  for (int r = 0; r < 4; r++) rr[r] = __shfl(linv, quad * 4 + r, 16);
#pragma unroll
  for (int nb = 0; nb < 4; nb++)
#pragma unroll
    for (int r = 0; r < 4; r++) {
      int rowg = q0 + wave * 16 + quad * 4 + r;
      ctx[(size_t)(b * SEQL + rowg) * D_EMBD + h * 64 + nb * 16 + lr] =
          f2bf(accO[nb][r] * rr[r]);
    }
}

extern "C" void kernel_launch(void* const* d_in, const int* in_sizes, int n_in,
                              void* d_out, int out_size, void* d_ws, size_t ws_size,
                              hipStream_t stream) {
  const float* x    = (const float*)d_in[0];
  const float* wq   = (const float*)d_in[1];
  const float* wk   = (const float*)d_in[2];
  const float* wv   = (const float*)d_in[3];
  const float* wo   = (const float*)d_in[4];
  const float* bo   = (const float*)d_in[5];
  const float* w1   = (const float*)d_in[6];
  const float* b1   = (const float*)d_in[7];
  const float* w2   = (const float*)d_in[8];
  const float* b2   = (const float*)d_in[9];
  const float* ln1s = (const float*)d_in[10];
  const float* ln1b = (const float*)d_in[11];
  const float* ln2s = (const float*)d_in[12];
  const float* ln2b = (const float*)d_in[13];
  float* out = (float*)d_out;

  char* base = (char*)d_ws;
  size_t off = 0;
  auto alloc = [&](size_t bytes) {
    char* r = base + off;
    off += (bytes + 255) & ~(size_t)255;
    return r;
  };
  u16*   wcat = (u16*)alloc((size_t)3072 * 1024 * 2);
  u16*   wob  = (u16*)alloc((size_t)1024 * 1024 * 2);
  u16*   w1b  = (u16*)alloc((size_t)4096 * 1024 * 2);
  u16*   w2b  = (u16*)alloc((size_t)1024 * 4096 * 2);
  u16*   xn   = (u16*)alloc((size_t)TOK * 1024 * 2);   // 8 MB
  u16*   qkv  = (u16*)alloc((size_t)TOK * 3072 * 2);   // 24 MB
  u16*   ctx  = (u16*)alloc((size_t)TOK * 1024 * 2);
  float* hbuf = (float*)alloc((size_t)TOK * 1024 * 4);
  u16*   ybuf = (u16*)alloc((size_t)TOK * 1024 * 2);
  u16*   gbuf = (u16*)alloc((size_t)TOK * 4096 * 2);
  // split-K bf16 partials (4 x 8 MB) overlay the dead xn+qkv region (32 MB):
  //   wo partials live attn->ln2f; w2 partials live w2gemm->reduce_w2.
  u16* woP = (u16*)xn;
  u16* w2P = (u16*)xn;

  // ONE prep launch: all weight conversions + LayerNorm1
  prep_kernel<<<16384, 256, 0, stream>>>(wq, wk, wv, wo, w1, w2,
                                         wcat, wob, w1b, w2b,
                                         x, ln1s, ln1b, xn);
  // qkv: dedicated 256x192-tile kernel -> (16,16) = 256 blocks = 1/CU exact
  gemm192<<<dim3(16, 16), 512, 0, stream>>>(xn, wcat, qkv, TOK, 3072, 1024);
  attn_kernel<<<1024, 256, 0, stream>>>(qkv, ctx);
  // wo: split-K=4 bf16 partials (qkv region now dead), KC=256 -> NT=4
  gemm256<EPI_BF16_PART><<<dim3(4, 16, 4), 512, 0, stream>>>(
      ctx, wob, woP, nullptr, TOK, 1024, 1024);
  // fused: h = x + sum(partials) + bo -> hbuf; ln2(h) -> ybuf
  ln2f_kernel<<<TOK, 256, 0, stream>>>(woP, x, bo, ln2s, ln2b, hbuf, ybuf);
  gemm256<EPI_BF16_GELU><<<dim3(16, 16), 512, 0, stream>>>(
      ybuf, w1b, gbuf, b1, TOK, 4096, 1024);
  gemm256<EPI_BF16_PART><<<dim3(4, 16, 4), 512, 0, stream>>>(
      gbuf, w2b, w2P, nullptr, TOK, 1024, 4096);
  reduce_w2_kernel<<<4096, 256, 0, stream>>>(w2P, hbuf, b2, out);
}